// Round 13
// baseline (910.791 us; speedup 1.0000x reference)
//
#include <hip/hip_runtime.h>
#include <hip/hip_bf16.h>
#include <hip/hip_cooperative_groups.h>
#include <math.h>

namespace cg = cooperative_groups;

// GCN stack: 3x [GCNConv + ReLU] + MLP head (64->32 relu ->40) + log_softmax.
// R13: two cooperative launches (R12 accounting: ~150us of 430 was launch
// gaps across 8 kernels; R11's fusion failure was the forced 64-VGPR cap,
// NOT fusion itself — no min-waves bound here, phases are 44-64 VGPR):
//   K1 csr_build: count -> scan -> scatter -> bucket CSR (3 grid.syncs)
//   K2 gnn_main:  gemm0 -> gather+gemm1 -> gather+gemm2 -> gather+head
// Head restructured LDS-first: each lane computes 4 h-channels over all 64
// inputs from LDS (kills the 96 shfl_xor/node fold = 4.8M bank conflicts);
// only 6 shfls/node remain (softmax scalars).

#define DIMF 64
#define BSH  9       // 512 nodes per bucket

// ---------------- K1: CSR build (cooperative) ----------------

struct CsrArgs {
    const int* src; const int* dst;
    int* partial; int* bucket_off; int* gcursor;
    unsigned int* ebuf; int* row_start; int* csr_src; float* dinv;
    int n, E, nbk;
};

__global__ __launch_bounds__(256) void csr_build(CsrArgs a)
{
    cg::grid_group grid = cg::this_grid();
    __shared__ int sh[512];
    __shared__ int sps[256];
    int t = threadIdx.x;
    int G = gridDim.x;
    int tile = (a.E + G - 1) / G;
    int estart = blockIdx.x * tile;
    int eend = min(a.E, estart + tile);

    // P1: per-block LDS histogram of dst buckets
    sh[t] = 0;
    __syncthreads();
    for (int e = estart + t; e < eend; e += 256)
        atomicAdd(&sh[a.dst[e] >> BSH], 1);
    __syncthreads();
    a.partial[blockIdx.x * 256 + t] = sh[t];
    grid.sync();

    // P2: block 0 scans bucket totals
    if (blockIdx.x == 0) {
        int sum = 0;
        for (int b = 0; b < G; b++) sum += a.partial[b * 256 + t];
        sps[t] = sum;
        __syncthreads();
        for (int off = 1; off < 256; off <<= 1) {
            int v = (t >= off) ? sps[t - off] : 0;
            __syncthreads();
            sps[t] += v;
            __syncthreads();
        }
        a.bucket_off[t] = sps[t] - sum;
        a.gcursor[t] = sps[t] - sum;
        if (t == 255) a.bucket_off[256] = sps[t];   // == E
    }
    grid.sync();

    // P3: scatter packed (src<<9 | dst&511) into bucket-contiguous ebuf
    sh[t] = atomicAdd(&a.gcursor[t], a.partial[blockIdx.x * 256 + t]);
    __syncthreads();
    for (int e = estart + t; e < eend; e += 256) {
        int d = a.dst[e];
        int p = atomicAdd(&sh[d >> BSH], 1);
        a.ebuf[p] = ((unsigned int)a.src[e] << BSH) | (unsigned int)(d & 511);
    }
    grid.sync();

    // P4: per-bucket local count/scan/place -> row_start, csr_src, dinv
    for (int blk = blockIdx.x; blk < a.nbk; blk += G) {
        int node0 = blk << BSH;
        sh[t] = 0; sh[t + 256] = 0;
        __syncthreads();
        int bs = a.bucket_off[blk], be = a.bucket_off[blk + 1];
        for (int i = bs + t; i < be; i += 256)
            atomicAdd(&sh[a.ebuf[i] & 511], 1);
        __syncthreads();
        int c0 = sh[2 * t], c1 = sh[2 * t + 1];
        sps[t] = c0 + c1;
        __syncthreads();
        for (int off = 1; off < 256; off <<= 1) {
            int v = (t >= off) ? sps[t - off] : 0;
            __syncthreads();
            sps[t] += v;
            __syncthreads();
        }
        int pexcl = sps[t] - (c0 + c1);
        int e0 = pexcl, e1 = pexcl + c0;
        int g0 = node0 + 2 * t, g1 = g0 + 1;
        if (g0 < a.n) { a.row_start[g0] = bs + e0; a.dinv[g0] = rsqrtf((float)c0 + 1.0f); }
        if (g1 < a.n) { a.row_start[g1] = bs + e1; a.dinv[g1] = rsqrtf((float)c1 + 1.0f); }
        __syncthreads();
        sh[2 * t] = e0; sh[2 * t + 1] = e1;      // local cursors
        __syncthreads();
        for (int i = bs + t; i < be; i += 256) {
            unsigned int pk = a.ebuf[i];
            int p = bs + atomicAdd(&sh[pk & 511], 1);
            a.csr_src[p] = (int)(pk >> BSH);
        }
        __syncthreads();
    }
    if (blockIdx.x == 0 && t == 0) a.row_start[a.n] = a.E;
}

// ---------------- K2: fused pipeline (cooperative) ----------------

struct MainArgs {
    const float* x;
    const int* row_start; const int* csr_src; const float* dinv;
    const float* W0; const float* b0;
    const float* W1; const float* b1;
    const float* W2; const float* b2;
    const float* Wp1; const float* bp1;
    const float* Wp2; const float* bp2;
    float* out;
    __hip_bfloat16* hpA; __hip_bfloat16* hpB;
    int n;
};

#define ADDROW(acc, v)                                                     \
    {                                                                      \
        acc[0] += __uint_as_float((v).x << 16);                            \
        acc[1] += __uint_as_float((v).x & 0xffff0000u);                    \
        acc[2] += __uint_as_float((v).y << 16);                            \
        acc[3] += __uint_as_float((v).y & 0xffff0000u);                    \
        acc[4] += __uint_as_float((v).z << 16);                            \
        acc[5] += __uint_as_float((v).z & 0xffff0000u);                    \
        acc[6] += __uint_as_float((v).w << 16);                            \
        acc[7] += __uint_as_float((v).w & 0xffff0000u);                    \
    }

// Gather 1 node's 8 features for this lane (4-deep unroll, R10 body).
#define GATHER_BODY(xv_out)                                                    \
    float xv_out[8];                                                           \
    {                                                                          \
        int rs = row_start[node];                                              \
        int re = row_start[node + 1];                                          \
        int deg = re - rs;                                                     \
        float a0[8], a1[8], a2[8], a3[8];                                      \
        _Pragma("unroll")                                                      \
        for (int i = 0; i < 8; i++) { a0[i]=0.f; a1[i]=0.f; a2[i]=0.f; a3[i]=0.f; } \
        {                                                                      \
            uint4 v = *(const uint4*)(hprime + (size_t)node * 32 + uoff);      \
            ADDROW(a0, v);                                                     \
        }                                                                      \
        int k = 0;                                                             \
        if (deg >= 4) {                                                        \
            int i0 = csr_src[rs], i1 = csr_src[rs + 1];                        \
            int i2 = csr_src[rs + 2], i3 = csr_src[rs + 3];                    \
            for (; k + 4 <= deg; k += 4) {                                     \
                int m0 = (k + 4 < deg) ? csr_src[rs + k + 4] : 0;              \
                int m1 = (k + 5 < deg) ? csr_src[rs + k + 5] : 0;              \
                int m2 = (k + 6 < deg) ? csr_src[rs + k + 6] : 0;              \
                int m3 = (k + 7 < deg) ? csr_src[rs + k + 7] : 0;              \
                uint4 v0 = *(const uint4*)(hprime + (size_t)i0 * 32 + uoff);   \
                uint4 v1 = *(const uint4*)(hprime + (size_t)i1 * 32 + uoff);   \
                uint4 v2 = *(const uint4*)(hprime + (size_t)i2 * 32 + uoff);   \
                uint4 v3 = *(const uint4*)(hprime + (size_t)i3 * 32 + uoff);   \
                ADDROW(a0, v0); ADDROW(a1, v1); ADDROW(a2, v2); ADDROW(a3, v3);\
                i0 = m0; i1 = m1; i2 = m2; i3 = m3;                            \
            }                                                                  \
        }                                                                      \
        for (; k < deg; k++) {                                                 \
            int idx = csr_src[rs + k];                                         \
            uint4 v = *(const uint4*)(hprime + (size_t)idx * 32 + uoff);       \
            ADDROW(a0, v);                                                     \
        }                                                                      \
        int f8 = uoff << 1;                                                    \
        float dv = dinv[node];                                                 \
        _Pragma("unroll")                                                      \
        for (int j = 0; j < 8; j++)                                            \
            xv_out[j] = fmaxf(fmaf(dv, a0[j] + a1[j] + a2[j] + a3[j],          \
                                   b[f8 + j]), 0.0f);                          \
    }

// Phase: gemm0 (f32 x -> hpA)
__device__ void p_gemm0(const float* __restrict__ xin, const float* __restrict__ W,
                        const float* __restrict__ dinv, __hip_bfloat16* __restrict__ hp,
                        int n, float* Ws, float (*Xs)[65])
{
    int t = threadIdx.x;
    for (int i = t; i < 4096; i += 256) Ws[i] = W[i];
    int col = t & 63, rbase = (t >> 6) * 8;
    int ntiles = (n + 31) >> 5;
    for (int tile = blockIdx.x; tile < ntiles; tile += gridDim.x) {
        int row0 = tile << 5;
        for (int i = t; i < 2048; i += 256) {
            int r = i >> 6, c = i & 63;
            int gr = row0 + r;
            Xs[r][c] = (gr < n) ? xin[(size_t)gr * DIMF + c] : 0.0f;
        }
        __syncthreads();
        float av[8];
#pragma unroll
        for (int rr = 0; rr < 8; rr++) av[rr] = 0.0f;
        for (int k = 0; k < 64; k++) {
            float w = Ws[k * 64 + col];
#pragma unroll
            for (int rr = 0; rr < 8; rr++)
                av[rr] = fmaf(Xs[rbase + rr][k], w, av[rr]);
        }
#pragma unroll
        for (int rr = 0; rr < 8; rr++) {
            int gr = row0 + rbase + rr;
            if (gr < n)
                hp[(size_t)gr * DIMF + col] = __float2bfloat16(av[rr] * dinv[gr]);
        }
        __syncthreads();
    }
}

// Phase: gather(l) + gemm(l+1), f32 through LDS
__device__ void p_gather_gemm(
    const unsigned int* __restrict__ hprime,
    const int* __restrict__ row_start, const int* __restrict__ csr_src,
    const float* __restrict__ dinv, const float* __restrict__ b,
    const float* __restrict__ Wn, __hip_bfloat16* __restrict__ hpout,
    int n, float* Ws, float (*Xs)[65])
{
    int t = threadIdx.x;
    for (int i = t; i < 4096; i += 256) Ws[i] = Wn[i];
    int wave = t >> 6, lane = t & 63;
    int slot = lane >> 3, o = lane & 7;
    int uoff = o << 2, ln = (wave << 3) + slot;
    int col = t & 63, rbase = (t >> 6) * 8;
    int ntiles = (n + 31) >> 5;
    for (int tile = blockIdx.x; tile < ntiles; tile += gridDim.x) {
        int row0 = tile << 5;
        int node = row0 + ln;
        int f8l = o << 3;
        if (node < n) {
            GATHER_BODY(xv)
#pragma unroll
            for (int j = 0; j < 8; j++) Xs[ln][f8l + j] = xv[j];
        } else {
#pragma unroll
            for (int j = 0; j < 8; j++) Xs[ln][f8l + j] = 0.0f;
        }
        __syncthreads();
        float av[8];
#pragma unroll
        for (int rr = 0; rr < 8; rr++) av[rr] = 0.0f;
        for (int k = 0; k < 64; k++) {
            float w = Ws[k * 64 + col];
#pragma unroll
            for (int rr = 0; rr < 8; rr++)
                av[rr] = fmaf(Xs[rbase + rr][k], w, av[rr]);
        }
#pragma unroll
        for (int rr = 0; rr < 8; rr++) {
            int gr = row0 + rbase + rr;
            if (gr < n)
                hpout[(size_t)gr * DIMF + col] = __float2bfloat16(av[rr] * dinv[gr]);
        }
        __syncthreads();
    }
}

// Phase: gather(2) + MLP head + log_softmax, LDS-first (no h-fold shfls)
__device__ void p_gather_head(
    const unsigned int* __restrict__ hprime,
    const int* __restrict__ row_start, const int* __restrict__ csr_src,
    const float* __restrict__ dinv, const float* __restrict__ b,
    const float* __restrict__ Wp1, const float* __restrict__ bp1,
    const float* __restrict__ Wp2, const float* __restrict__ bp2,
    float* __restrict__ out, int n, float* sm, float (*Xs)[65], float (*Hs)[33])
{
    float* W1s = sm;            // 2048
    float* W2s = sm + 2048;     // 1280
    float* b1s = sm + 3328;     // 32
    float* b2s = sm + 3360;     // 40
    int t = threadIdx.x;
    for (int i = t; i < 2048; i += 256) W1s[i] = Wp1[i];
    for (int i = t; i < 1280; i += 256) W2s[i] = Wp2[i];
    if (t < 32) b1s[t] = bp1[t];
    if (t < 40) b2s[t] = bp2[t];
    int wave = t >> 6, lane = t & 63;
    int slot = lane >> 3, o = lane & 7;
    int uoff = o << 2, ln = (wave << 3) + slot;
    int ntiles = (n + 31) >> 5;
    for (int tile = blockIdx.x; tile < ntiles; tile += gridDim.x) {
        int row0 = tile << 5;
        int node = row0 + ln;
        int f8l = o << 3;
        if (node < n) {
            GATHER_BODY(xv)
#pragma unroll
            for (int j = 0; j < 8; j++) Xs[ln][f8l + j] = xv[j];
        } else {
#pragma unroll
            for (int j = 0; j < 8; j++) Xs[ln][f8l + j] = 0.0f;
        }
        __syncthreads();
        // lane computes h channels o*4 .. o*4+3 over all 64 inputs
        float h[4];
#pragma unroll
        for (int m = 0; m < 4; m++) h[m] = b1s[o * 4 + m];
        for (int k = 0; k < 64; k++) {
            float xk = Xs[ln][k];
#pragma unroll
            for (int m = 0; m < 4; m++)
                h[m] = fmaf(xk, W1s[k * 32 + o * 4 + m], h[m]);
        }
#pragma unroll
        for (int m = 0; m < 4; m++) Hs[ln][o * 4 + m] = fmaxf(h[m], 0.0f);
        __syncthreads();
        if (node < n) {
            float oo[5];
#pragma unroll
            for (int m = 0; m < 5; m++) {
                int j5 = o * 5 + m;
                float acc = b2s[j5];
#pragma unroll
                for (int k = 0; k < 32; k++)
                    acc = fmaf(Hs[ln][k], W2s[k * 40 + j5], acc);
                oo[m] = acc;
            }
            float mx = oo[0];
#pragma unroll
            for (int m = 1; m < 5; m++) mx = fmaxf(mx, oo[m]);
#pragma unroll
            for (int mask = 1; mask <= 4; mask <<= 1) mx = fmaxf(mx, __shfl_xor(mx, mask));
            float se = 0.0f;
#pragma unroll
            for (int m = 0; m < 5; m++) se += expf(oo[m] - mx);
#pragma unroll
            for (int mask = 1; mask <= 4; mask <<= 1) se += __shfl_xor(se, mask);
            float lse = logf(se) + mx;
            float* op = out + (size_t)node * 40 + o * 5;
#pragma unroll
            for (int m = 0; m < 5; m++) op[m] = oo[m] - lse;
        }
        __syncthreads();
    }
}

__global__ __launch_bounds__(256) void gnn_main(MainArgs a)
{
    cg::grid_group grid = cg::this_grid();
    __shared__ float sWs[4096];       // 16 KB
    __shared__ float sXs[32][65];     // 8.3 KB
    __shared__ float sHs[32][33];     // 4.2 KB

    p_gemm0(a.x, a.W0, a.dinv, a.hpA, a.n, sWs, sXs);
    grid.sync();
    p_gather_gemm((const unsigned int*)a.hpA, a.row_start, a.csr_src, a.dinv,
                  a.b0, a.W1, a.hpB, a.n, sWs, sXs);
    grid.sync();
    p_gather_gemm((const unsigned int*)a.hpB, a.row_start, a.csr_src, a.dinv,
                  a.b1, a.W2, a.hpA, a.n, sWs, sXs);
    grid.sync();
    p_gather_head((const unsigned int*)a.hpA, a.row_start, a.csr_src, a.dinv,
                  a.b2, a.Wp1, a.bp1, a.Wp2, a.bp2, a.out, a.n, sWs, sXs, sHs);
}

extern "C" void kernel_launch(void* const* d_in, const int* in_sizes, int n_in,
                              void* d_out, int out_size, void* d_ws, size_t ws_size,
                              hipStream_t stream)
{
    const float* x  = (const float*)d_in[0];
    const int*   ei = (const int*)d_in[1];
    const int E = in_sizes[1] / 2;
    const int n = in_sizes[0] / DIMF;
    const int* src = ei;
    const int* dst = ei + E;
    float* out = (float*)d_out;

    const int nbk = (n + 511) >> BSH;

    // Workspace: partial[512*256] | bucket_off[257] | gcursor[256] |
    //            row_start[n+1] | dinv[n] | csr_src[E] |
    //            hpA[n*64 bf16] | hpB[n*64 bf16] (ebuf aliases hpB)
    char* p = (char*)d_ws;
    int* partial    = (int*)p;                p += (size_t)512 * 256 * 4;
    int* bucket_off = (int*)p;                p += 257 * 4;
    int* gcursor    = (int*)p;                p += 256 * 4;
    p = (char*)(((size_t)p + 15) & ~(size_t)15);
    int* row_start  = (int*)p;                p += (size_t)(n + 1) * 4;
    float* dinv     = (float*)p;              p += (size_t)n * 4;
    p = (char*)(((size_t)p + 15) & ~(size_t)15);
    int* csr_src    = (int*)p;                p += (size_t)E * 4;
    p = (char*)(((size_t)p + 15) & ~(size_t)15);
    __hip_bfloat16* hpA = (__hip_bfloat16*)p; p += (size_t)n * DIMF * 2;
    p = (char*)(((size_t)p + 15) & ~(size_t)15);
    __hip_bfloat16* hpB = (__hip_bfloat16*)p;
    unsigned int* ebuf  = (unsigned int*)hpB;   // dead once gnn_main P1 runs

    // --- K1: CSR build (cooperative) ---
    CsrArgs ca;
    ca.src = src; ca.dst = dst; ca.partial = partial; ca.bucket_off = bucket_off;
    ca.gcursor = gcursor; ca.ebuf = ebuf; ca.row_start = row_start;
    ca.csr_src = csr_src; ca.dinv = dinv; ca.n = n; ca.E = E; ca.nbk = nbk;

    int mb1 = 0;
    hipOccupancyMaxActiveBlocksPerMultiprocessor(&mb1, csr_build, 256, 0);
    if (mb1 < 1) mb1 = 1;
    int g1 = mb1 * 256;
    if (g1 > 512) g1 = 512;    // partial[] sized for 512 blocks
    void* ka1[] = { (void*)&ca };
    hipLaunchCooperativeKernel((const void*)csr_build, dim3(g1), dim3(256),
                               ka1, 0, stream);

    // --- K2: fused pipeline (cooperative) ---
    MainArgs ma;
    ma.x = x; ma.row_start = row_start; ma.csr_src = csr_src; ma.dinv = dinv;
    ma.W0 = (const float*)d_in[3];  ma.b0 = (const float*)d_in[4];
    ma.W1 = (const float*)d_in[5];  ma.b1 = (const float*)d_in[6];
    ma.W2 = (const float*)d_in[7];  ma.b2 = (const float*)d_in[8];
    ma.Wp1 = (const float*)d_in[9]; ma.bp1 = (const float*)d_in[10];
    ma.Wp2 = (const float*)d_in[11];ma.bp2 = (const float*)d_in[12];
    ma.out = out; ma.hpA = hpA; ma.hpB = hpB; ma.n = n;

    int mb2 = 0;
    hipOccupancyMaxActiveBlocksPerMultiprocessor(&mb2, gnn_main, 256, 0);
    if (mb2 < 1) mb2 = 1;
    int g2 = mb2 * 256;
    int ntiles = (n + 31) / 32;
    if (g2 > ntiles) g2 = ntiles;
    void* ka2[] = { (void*)&ma };
    hipLaunchCooperativeKernel((const void*)gnn_main, dim3(g2), dim3(256),
                               ka2, 0, stream);
}

// Round 14
// 424.755 us; speedup vs baseline: 2.1443x; 2.1443x over previous
//
#include <hip/hip_runtime.h>
#include <hip/hip_bf16.h>
#include <math.h>

// GCN stack: 3x [GCNConv + ReLU] + MLP head (64->32 relu ->40) + log_softmax.
// R14: R12 structure (pairwise fusion, 8 plain dispatches — both cooperative
// megakernel attempts R11/R13 lost 2x+; grid.sync on 8 XCDs is expensive).
// Only change vs R12: gather_head uses the LDS-first head (verified in R13):
// kills the 96 shfl_xor/node h-fold = 4.8M LDS bank conflicts.
//   K0 = gemm0, K1/K2 = gather+gemm (f32 via LDS), K3 = gather+head.

#define DIMF 64
#define NBA  200     // blocks for bucket count/scatter
#define BSH  9       // 512 nodes per bucket

// ---------------- CSR build (bucketed, packed ebuf) ----------------

__global__ __launch_bounds__(256) void bucket_count(
    const int* __restrict__ dst, int* __restrict__ partial, int E, int tile)
{
    __shared__ int h[256];
    int t = threadIdx.x;
    h[t] = 0;
    __syncthreads();
    int estart = blockIdx.x * tile;
    int eend = min(E, estart + tile);
    for (int e = estart + t; e < eend; e += 256)
        atomicAdd(&h[dst[e] >> BSH], 1);
    __syncthreads();
    partial[blockIdx.x * 256 + t] = h[t];
}

__global__ __launch_bounds__(256) void bucket_scan(
    const int* __restrict__ partial, int* __restrict__ bucket_off,
    int* __restrict__ gcursor, int nba)
{
    __shared__ int s[256];
    int t = threadIdx.x;
    int sum = 0;
    for (int b = 0; b < nba; b++) sum += partial[b * 256 + t];
    s[t] = sum;
    __syncthreads();
    for (int off = 1; off < 256; off <<= 1) {
        int v = (t >= off) ? s[t - off] : 0;
        __syncthreads();
        s[t] += v;
        __syncthreads();
    }
    int excl = s[t] - sum;
    bucket_off[t] = excl;
    gcursor[t] = excl;
    if (t == 255) bucket_off[256] = s[t];   // == E
}

__global__ __launch_bounds__(256) void bucket_scatter(
    const int* __restrict__ src, const int* __restrict__ dst,
    const int* __restrict__ partial, int* __restrict__ gcursor,
    unsigned int* __restrict__ ebuf, int E, int tile)
{
    __shared__ int h[256];
    int t = threadIdx.x;
    h[t] = atomicAdd(&gcursor[t], partial[blockIdx.x * 256 + t]);
    __syncthreads();
    int estart = blockIdx.x * tile;
    int eend = min(E, estart + tile);
    for (int e = estart + t; e < eend; e += 256) {
        int d = dst[e];
        int p = atomicAdd(&h[d >> BSH], 1);
        ebuf[p] = ((unsigned int)src[e] << BSH) | (unsigned int)(d & 511);
    }
}

__global__ __launch_bounds__(256) void bucket_csr(
    const unsigned int* __restrict__ ebuf, const int* __restrict__ bucket_off,
    int* __restrict__ row_start, int* __restrict__ csr_src,
    float* __restrict__ dinv, int n, int E)
{
    __shared__ int cnt[512];
    __shared__ int ps[256];
    int t = threadIdx.x;
    int blk = blockIdx.x;
    int node0 = blk << BSH;
    cnt[t] = 0; cnt[t + 256] = 0;
    __syncthreads();
    int bs = bucket_off[blk], be = bucket_off[blk + 1];
    for (int i = bs + t; i < be; i += 256)
        atomicAdd(&cnt[ebuf[i] & 511], 1);
    __syncthreads();
    int c0 = cnt[2 * t], c1 = cnt[2 * t + 1];
    ps[t] = c0 + c1;
    __syncthreads();
    for (int off = 1; off < 256; off <<= 1) {
        int v = (t >= off) ? ps[t - off] : 0;
        __syncthreads();
        ps[t] += v;
        __syncthreads();
    }
    int pexcl = ps[t] - (c0 + c1);
    int e0 = pexcl, e1 = pexcl + c0;
    int g0 = node0 + 2 * t, g1 = g0 + 1;
    if (g0 < n) { row_start[g0] = bs + e0; dinv[g0] = rsqrtf((float)c0 + 1.0f); }
    if (g1 < n) { row_start[g1] = bs + e1; dinv[g1] = rsqrtf((float)c1 + 1.0f); }
    __syncthreads();
    cnt[2 * t] = e0; cnt[2 * t + 1] = e1;    // cnt becomes local cursor
    __syncthreads();
    for (int i = bs + t; i < be; i += 256) {
        unsigned int pk = ebuf[i];
        int p = bs + atomicAdd(&cnt[pk & 511], 1);
        csr_src[p] = (int)(pk >> BSH);
    }
    if (blk == gridDim.x - 1 && t == 0) row_start[n] = E;
}

// ---------------- K0: gemm0 (f32 x -> hpA bf16) ----------------

__global__ __launch_bounds__(256) void gemm_scale_f32(
    const float* __restrict__ xin, const float* __restrict__ W,
    const float* __restrict__ dinv, __hip_bfloat16* __restrict__ hprime, int n)
{
    __shared__ float Ws[64 * 64];
    __shared__ float Xs[32][65];
    int t = threadIdx.x;
    for (int i = t; i < 4096; i += 256) Ws[i] = W[i];
    int row0 = blockIdx.x * 32;
    for (int i = t; i < 2048; i += 256) {
        int r = i >> 6, c = i & 63;
        int gr = row0 + r;
        Xs[r][c] = (gr < n) ? xin[(size_t)gr * DIMF + c] : 0.0f;
    }
    __syncthreads();
    int col = t & 63;
    int rbase = (t >> 6) * 8;
    float av[8];
#pragma unroll
    for (int rr = 0; rr < 8; rr++) av[rr] = 0.0f;
    for (int k = 0; k < 64; k++) {
        float w = Ws[k * 64 + col];
#pragma unroll
        for (int rr = 0; rr < 8; rr++)
            av[rr] = fmaf(Xs[rbase + rr][k], w, av[rr]);
    }
#pragma unroll
    for (int rr = 0; rr < 8; rr++) {
        int gr = row0 + rbase + rr;
        if (gr < n)
            hprime[(size_t)gr * DIMF + col] = __float2bfloat16(av[rr] * dinv[gr]);
    }
}

// ---------------- shared gather body (4-deep unroll) ----------------

#define ADDROW(a, v)                                                       \
    {                                                                      \
        a[0] += __uint_as_float((v).x << 16);                              \
        a[1] += __uint_as_float((v).x & 0xffff0000u);                      \
        a[2] += __uint_as_float((v).y << 16);                              \
        a[3] += __uint_as_float((v).y & 0xffff0000u);                      \
        a[4] += __uint_as_float((v).z << 16);                              \
        a[5] += __uint_as_float((v).z & 0xffff0000u);                      \
        a[6] += __uint_as_float((v).w << 16);                              \
        a[7] += __uint_as_float((v).w & 0xffff0000u);                      \
    }

#define GATHER_BODY(xv_out)                                                    \
    float xv_out[8];                                                           \
    {                                                                          \
        int rs = row_start[node];                                              \
        int re = row_start[node + 1];                                          \
        int deg = re - rs;                                                     \
        float a0[8], a1[8], a2[8], a3[8];                                      \
        _Pragma("unroll")                                                      \
        for (int i = 0; i < 8; i++) { a0[i]=0.f; a1[i]=0.f; a2[i]=0.f; a3[i]=0.f; } \
        {                                                                      \
            uint4 v = *(const uint4*)(hprime + (size_t)node * 32 + uoff);      \
            ADDROW(a0, v);                                                     \
        }                                                                      \
        int k = 0;                                                             \
        if (deg >= 4) {                                                        \
            int i0 = csr_src[rs], i1 = csr_src[rs + 1];                        \
            int i2 = csr_src[rs + 2], i3 = csr_src[rs + 3];                    \
            for (; k + 4 <= deg; k += 4) {                                     \
                int m0 = (k + 4 < deg) ? csr_src[rs + k + 4] : 0;              \
                int m1 = (k + 5 < deg) ? csr_src[rs + k + 5] : 0;              \
                int m2 = (k + 6 < deg) ? csr_src[rs + k + 6] : 0;              \
                int m3 = (k + 7 < deg) ? csr_src[rs + k + 7] : 0;              \
                uint4 v0 = *(const uint4*)(hprime + (size_t)i0 * 32 + uoff);   \
                uint4 v1 = *(const uint4*)(hprime + (size_t)i1 * 32 + uoff);   \
                uint4 v2 = *(const uint4*)(hprime + (size_t)i2 * 32 + uoff);   \
                uint4 v3 = *(const uint4*)(hprime + (size_t)i3 * 32 + uoff);   \
                ADDROW(a0, v0); ADDROW(a1, v1); ADDROW(a2, v2); ADDROW(a3, v3);\
                i0 = m0; i1 = m1; i2 = m2; i3 = m3;                            \
            }                                                                  \
        }                                                                      \
        for (; k < deg; k++) {                                                 \
            int idx = csr_src[rs + k];                                         \
            uint4 v = *(const uint4*)(hprime + (size_t)idx * 32 + uoff);       \
            ADDROW(a0, v);                                                     \
        }                                                                      \
        int f8 = uoff << 1;                                                    \
        float dv = dinv[node];                                                 \
        _Pragma("unroll")                                                      \
        for (int j = 0; j < 8; j++)                                            \
            xv_out[j] = fmaxf(fmaf(dv, a0[j] + a1[j] + a2[j] + a3[j],          \
                                   b[f8 + j]), 0.0f);                          \
    }

// ---------------- K1/K2: gather(l) + gemm(l+1), f32 through LDS ----------

__global__ __launch_bounds__(256) void gather_gemm(
    const unsigned int* __restrict__ hprime,  // hp(l) bf16x2, 32 uints/row
    const int* __restrict__ row_start, const int* __restrict__ csr_src,
    const float* __restrict__ dinv, const float* __restrict__ b,   // b(l)
    const float* __restrict__ Wn,                                  // W(l+1)
    __hip_bfloat16* __restrict__ hpout, int n)
{
    __shared__ float Ws[64 * 64];   // 16 KB
    __shared__ float Xs[32][65];    // 8.3 KB
    int t = threadIdx.x;
    for (int i = t; i < 4096; i += 256) Ws[i] = Wn[i];

    int wave = t >> 6;
    int lane = t & 63;
    int slot = lane >> 3;
    int o    = lane & 7;
    int uoff = o << 2;
    int ln   = (wave << 3) + slot;          // local node 0..31
    int row0 = blockIdx.x * 32;
    int node = row0 + ln;
    int f8l  = o << 3;

    if (node < n) {
        GATHER_BODY(xv)
#pragma unroll
        for (int j = 0; j < 8; j++) Xs[ln][f8l + j] = xv[j];
    } else {
#pragma unroll
        for (int j = 0; j < 8; j++) Xs[ln][f8l + j] = 0.0f;
    }
    __syncthreads();

    int col = t & 63;
    int rbase = (t >> 6) * 8;
    float av[8];
#pragma unroll
    for (int rr = 0; rr < 8; rr++) av[rr] = 0.0f;
    for (int k = 0; k < 64; k++) {
        float w = Ws[k * 64 + col];
#pragma unroll
        for (int rr = 0; rr < 8; rr++)
            av[rr] = fmaf(Xs[rbase + rr][k], w, av[rr]);
    }
#pragma unroll
    for (int rr = 0; rr < 8; rr++) {
        int gr = row0 + rbase + rr;
        if (gr < n)
            hpout[(size_t)gr * DIMF + col] = __float2bfloat16(av[rr] * dinv[gr]);
    }
}

// ---------------- K3: gather(2) + MLP head, LDS-first (R13-verified) -----
// Gather -> Xs; lane computes 4 h-channels over 64 inputs (broadcast W1
// reads, no shfl fold); Hs via LDS (same-wave, no extra sync); 5 logits per
// lane; 6 shfls/node for softmax scalars only.

__global__ __launch_bounds__(256) void gather_head(
    const unsigned int* __restrict__ hprime,  // hp(2) bf16x2
    const int* __restrict__ row_start, const int* __restrict__ csr_src,
    const float* __restrict__ dinv, const float* __restrict__ b,   // b(2)
    const float* __restrict__ Wp1, const float* __restrict__ bp1,
    const float* __restrict__ Wp2, const float* __restrict__ bp2,
    float* __restrict__ out, int n)
{
    __shared__ float W1s[64 * 32];   // 8 KB
    __shared__ float W2s[32 * 40];   // 5 KB
    __shared__ float b1s[32], b2s[40];
    __shared__ float Xs[32][65];     // 8.3 KB
    __shared__ float Hs[32][33];     // 4.2 KB
    int t = threadIdx.x;
    for (int i = t; i < 2048; i += 256) W1s[i] = Wp1[i];
    for (int i = t; i < 1280; i += 256) W2s[i] = Wp2[i];
    if (t < 32) b1s[t] = bp1[t];
    if (t < 40) b2s[t] = bp2[t];

    int wave = t >> 6;
    int lane = t & 63;
    int slot = lane >> 3;
    int o    = lane & 7;
    int uoff = o << 2;
    int ln   = (wave << 3) + slot;
    int node = blockIdx.x * 32 + ln;
    int f8l  = o << 3;

    if (node < n) {
        GATHER_BODY(xv)
#pragma unroll
        for (int j = 0; j < 8; j++) Xs[ln][f8l + j] = xv[j];
    } else {
#pragma unroll
        for (int j = 0; j < 8; j++) Xs[ln][f8l + j] = 0.0f;
    }
    __syncthreads();   // Xs complete + weights staged

    // lane computes h channels o*4 .. o*4+3 over all 64 inputs
    float h[4];
#pragma unroll
    for (int m = 0; m < 4; m++) h[m] = b1s[o * 4 + m];
    for (int k = 0; k < 64; k++) {
        float xk = Xs[ln][k];
#pragma unroll
        for (int m = 0; m < 4; m++)
            h[m] = fmaf(xk, W1s[k * 32 + o * 4 + m], h[m]);
    }
#pragma unroll
    for (int m = 0; m < 4; m++) Hs[ln][o * 4 + m] = fmaxf(h[m], 0.0f);
    // Hs written/read by the same wave: no __syncthreads needed

    if (node < n) {
        float oo[5];
#pragma unroll
        for (int m = 0; m < 5; m++) {
            int j5 = o * 5 + m;
            float acc = b2s[j5];
#pragma unroll
            for (int k = 0; k < 32; k++)
                acc = fmaf(Hs[ln][k], W2s[k * 40 + j5], acc);
            oo[m] = acc;
        }
        float mx = oo[0];
#pragma unroll
        for (int m = 1; m < 5; m++) mx = fmaxf(mx, oo[m]);
#pragma unroll
        for (int mask = 1; mask <= 4; mask <<= 1) mx = fmaxf(mx, __shfl_xor(mx, mask));
        float se = 0.0f;
#pragma unroll
        for (int m = 0; m < 5; m++) se += expf(oo[m] - mx);
#pragma unroll
        for (int mask = 1; mask <= 4; mask <<= 1) se += __shfl_xor(se, mask);
        float lse = logf(se) + mx;
        float* op = out + (size_t)node * 40 + o * 5;
#pragma unroll
        for (int m = 0; m < 5; m++) op[m] = oo[m] - lse;
    }
}

extern "C" void kernel_launch(void* const* d_in, const int* in_sizes, int n_in,
                              void* d_out, int out_size, void* d_ws, size_t ws_size,
                              hipStream_t stream)
{
    const float* x  = (const float*)d_in[0];
    const int*   ei = (const int*)d_in[1];
    const int E = in_sizes[1] / 2;
    const int n = in_sizes[0] / DIMF;
    const int* src = ei;
    const int* dst = ei + E;
    const float* W0 = (const float*)d_in[3];  const float* b0 = (const float*)d_in[4];
    const float* W1 = (const float*)d_in[5];  const float* b1 = (const float*)d_in[6];
    const float* W2 = (const float*)d_in[7];  const float* b2 = (const float*)d_in[8];
    const float* Wp1 = (const float*)d_in[9];  const float* bp1 = (const float*)d_in[10];
    const float* Wp2 = (const float*)d_in[11]; const float* bp2 = (const float*)d_in[12];
    float* out = (float*)d_out;

    const int NBK  = (n + 511) >> BSH;            // buckets (<= 256)
    const int tile = (E + NBA - 1) / NBA;

    // Workspace: partial[NBA*256] | bucket_off[257] | gcursor[256] |
    //            row_start[n+1] | dinv[n] | csr_src[E] |
    //            hpA[n*64 bf16] | hpB[n*64 bf16]  (ebuf[E uint] aliases hpB)
    char* p = (char*)d_ws;
    int* partial    = (int*)p;                p += (size_t)NBA * 256 * 4;
    int* bucket_off = (int*)p;                p += 257 * 4;
    int* gcursor    = (int*)p;                p += 256 * 4;
    p = (char*)(((size_t)p + 15) & ~(size_t)15);
    int* row_start  = (int*)p;                p += (size_t)(n + 1) * 4;
    float* dinv     = (float*)p;              p += (size_t)n * 4;
    p = (char*)(((size_t)p + 15) & ~(size_t)15);
    int* csr_src    = (int*)p;                p += (size_t)E * 4;
    p = (char*)(((size_t)p + 15) & ~(size_t)15);
    __hip_bfloat16* hpA = (__hip_bfloat16*)p; p += (size_t)n * DIMF * 2;
    p = (char*)(((size_t)p + 15) & ~(size_t)15);
    __hip_bfloat16* hpB = (__hip_bfloat16*)p;
    unsigned int* ebuf  = (unsigned int*)hpB;  // dead once K1 writes hpB

    const int nblk = (n + 31) / 32;

    // --- CSR build ---
    hipLaunchKernelGGL(bucket_count,   dim3(NBA), dim3(256), 0, stream, dst, partial, E, tile);
    hipLaunchKernelGGL(bucket_scan,    dim3(1),   dim3(256), 0, stream, partial, bucket_off, gcursor, NBA);
    hipLaunchKernelGGL(bucket_scatter, dim3(NBA), dim3(256), 0, stream, src, dst, partial, gcursor, ebuf, E, tile);
    hipLaunchKernelGGL(bucket_csr,     dim3(NBK), dim3(256), 0, stream, ebuf, bucket_off,
                       row_start, csr_src, dinv, n, E);

    // --- fused pipeline: K0, K1, K2, K3 ---
    hipLaunchKernelGGL(gemm_scale_f32, dim3(nblk), dim3(256), 0, stream,
                       x, W0, dinv, hpA, n);
    hipLaunchKernelGGL(gather_gemm, dim3(nblk), dim3(256), 0, stream,
                       (const unsigned int*)hpA, row_start, csr_src, dinv, b0,
                       W1, hpB, n);
    hipLaunchKernelGGL(gather_gemm, dim3(nblk), dim3(256), 0, stream,
                       (const unsigned int*)hpB, row_start, csr_src, dinv, b1,
                       W2, hpA, n);
    hipLaunchKernelGGL(gather_head, dim3(nblk), dim3(256), 0, stream,
                       (const unsigned int*)hpA, row_start, csr_src, dinv, b2,
                       Wp1, bp1, Wp2, bp2, out, n);
}